// Round 7
// baseline (65.468 us; speedup 1.0000x reference)
//
#include <hip/hip_runtime.h>
#include <cmath>

typedef unsigned short u16;
typedef __attribute__((ext_vector_type(8))) short s8v;    // 8 bf16 (4 VGPRs)
typedef __attribute__((ext_vector_type(4))) float f4v;    // 16x16 acc / float4
typedef __attribute__((ext_vector_type(16))) float f16v;  // 32x32 acc

__device__ __forceinline__ u16 f2bf(float f) {
    union { float f; unsigned u; } v; v.f = f;
    unsigned r = v.u + 0x7FFFu + ((v.u >> 16) & 1u);   // RNE
    return (u16)(r >> 16);
}
// fast tanh: 1 - 2/(1+exp2(2x*log2e)); |err| ~1e-6
__device__ __forceinline__ float tanh_fast(float x) {
    float e = __builtin_amdgcn_exp2f(x * 2.88539008177792681f);
    return 1.f - 2.f * __builtin_amdgcn_rcpf(1.f + e);
}
// 16x16 subtile swizzled slot (gemm1 input staging; verified R5)
__device__ __forceinline__ int wslot(int row, int c) {
    return ((((c >> 2) << 6) | ((c & 3) << 4) | (row & 15)) ^ c);
}
// fragment-layout flat u16 index for element (n,k) of an n-major matrix:
// frag tile nt=n>>5, kk=k>>4; lane = (n&31) + ((k>>3)&1)*32; j = k&7
__device__ __forceinline__ size_t fragoff(int n, int k) {
    return (((size_t)(n >> 5) * 64 + (k >> 4)) * 64 + (n & 31) + (((k >> 3) & 1) << 5)) * 8 + (k & 7);
}

// ---------------------------------------------------------------------------
// prep (grid 32x32, 256 thr):
//  all blocks : W2Tf[frag(n,k)]=bf16(W2[k][n]); VTf[frag(q,p)]=bf16(W2[p][q]*U[q][p]),
//               U = W3 @ W1 ; xb = bf16(x[:,1:])
//  by==0      : W1T[p][i] bf16 row-major; zero trJ
//  by==1      : W3Tf[frag(n,k)] = bf16(W3[k][n])
// ---------------------------------------------------------------------------
__launch_bounds__(256)
__global__ void cnf_prep(const float* __restrict__ x, const float* __restrict__ W1,
                         const float* __restrict__ W2, const float* __restrict__ W3,
                         u16* __restrict__ W2Tf, u16* __restrict__ VTf,
                         u16* __restrict__ xb, u16* __restrict__ W1T,
                         u16* __restrict__ W3Tf, float* __restrict__ trJ)
{
    __shared__ float w2s[32][33];
    __shared__ float w1s[32][68];
    const int a = blockIdx.x * 32;   // p / k (rows of W2)
    const int b = blockIdx.y * 32;   // q / n (cols of W2)
    const int t = threadIdx.x;

    #pragma unroll
    for (int it = 0; it < 4; ++it) {
        int idx = t + it * 256;
        w2s[idx >> 5][idx & 31] = W2[(a + (idx >> 5)) * 1024 + b + (idx & 31)];
    }
    #pragma unroll
    for (int it = 0; it < 8; ++it) {
        int idx = t + it * 256;
        w1s[idx & 31][idx >> 5] = W1[(idx >> 5) * 1024 + a + (idx & 31)];
    }
    __syncthreads();

    #pragma unroll
    for (int it = 0; it < 4; ++it) {
        int idx = t + it * 256;
        int rr = idx >> 5, cc = idx & 31;
        W2Tf[fragoff(b + rr, a + cc)] = f2bf(w2s[cc][rr]);
    }
    #pragma unroll
    for (int it = 0; it < 4; ++it) {
        int idx = t + it * 256;
        int qq = idx >> 5, pp = idx & 31;
        const float* w3row = W3 + (b + qq) * 64;
        float u = 0.f;
        #pragma unroll
        for (int i4 = 0; i4 < 16; ++i4) {
            f4v wv  = *(const f4v*)&w1s[pp][i4 * 4];
            f4v w3v = *(const f4v*)&w3row[i4 * 4];
            u += wv[0]*w3v[0] + wv[1]*w3v[1] + wv[2]*w3v[2] + wv[3]*w3v[3];
        }
        VTf[fragoff(b + qq, a + pp)] = f2bf(w2s[pp][qq] * u);
    }
    {
        int bid = blockIdx.y * 32 + blockIdx.x;
        int e = bid * 256 + t;
        xb[e] = f2bf(x[(e >> 6) * 65 + 1 + (e & 63)]);
    }
    if (blockIdx.y == 0) {
        int pp = t >> 3, i0 = (t & 7) * 8;
        s8v v;
        #pragma unroll
        for (int j = 0; j < 8; ++j) v[j] = (short)f2bf(w1s[pp][i0 + j]);
        *(s8v*)&W1T[(a + pp) * 64 + i0] = v;
        if (t < 128) trJ[blockIdx.x * 128 + t] = 0.f;
    }
    if (blockIdx.y == 1) {
        int idx = blockIdx.x * 256 + t;
        int n = idx & 63, k0 = (idx >> 6) * 8;
        s8v v;
        #pragma unroll
        for (int j = 0; j < 8; ++j) v[j] = (short)f2bf(W3[(k0 + j) * 64 + n]);
        *(s8v*)&W3Tf[fragoff(n, k0)] = v;
    }
}

// ---------------------------------------------------------------------------
// gemm1 (MFMA 16x16x32): h1 = tanh(xb @ W1T^T + b1), g1 = 1-h1^2
// OUTPUT IN FRAGMENT LAYOUT (h1f/g1f) via LDS transpose + coalesced s8v stores.
// Block 128 rows x 64 cols, grid (32,16), 4 waves 2x2.
// ---------------------------------------------------------------------------
__launch_bounds__(256)
__global__ void cnf_gemm1(const u16* __restrict__ xb, const u16* __restrict__ W1T,
                          const float* __restrict__ b1,
                          u16* __restrict__ h1f, u16* __restrict__ g1f)
{
    __shared__ __align__(16) u16 lds[12 * 1024];   // 24 KB input staging
    __shared__ __align__(16) u16 hls[128 * 64];    // 16 KB
    __shared__ __align__(16) u16 gls[128 * 64];    // 16 KB
    const int t = threadIdx.x;
    const int wave = t >> 6, lane = t & 63;
    const int wm = wave >> 1, wn = wave & 1;
    const int g = lane >> 4, lr = lane & 15;
    const int arow0 = blockIdx.x * 128, bcol0 = blockIdx.y * 64;

    #pragma unroll
    for (int i = 0; i < 4; ++i) {
        int ch = t + i * 256, row = ch >> 3, c = ch & 7;
        *(s8v*)&lds[(row >> 4) * 1024 + wslot(row, c) * 8] =
            *(const s8v*)&xb[(arow0 + row) * 64 + c * 8];
    }
    #pragma unroll
    for (int i = 0; i < 2; ++i) {
        int ch = t + i * 256, row = ch >> 3, c = ch & 7;
        *(s8v*)&lds[(8 + (row >> 4)) * 1024 + wslot(row, c) * 8] =
            *(const s8v*)&W1T[(bcol0 + row) * 64 + c * 8];
    }
    __syncthreads();

    f4v acc[4][2];
    #pragma unroll
    for (int mi = 0; mi < 4; ++mi)
        #pragma unroll
        for (int ni = 0; ni < 2; ++ni) acc[mi][ni] = f4v{0.f,0.f,0.f,0.f};

    #pragma unroll
    for (int ks = 0; ks < 2; ++ks) {
        const int lo = (ks * 64 + (lane ^ ((ks * 4 + g) & 7))) * 8;
        s8v af[4], bf[2];
        #pragma unroll
        for (int mi = 0; mi < 4; ++mi) af[mi] = *(const s8v*)&lds[(wm * 4 + mi) * 1024 + lo];
        #pragma unroll
        for (int ni = 0; ni < 2; ++ni) bf[ni] = *(const s8v*)&lds[(8 + wn * 2 + ni) * 1024 + lo];
        #pragma unroll
        for (int mi = 0; mi < 4; ++mi)
            #pragma unroll
            for (int ni = 0; ni < 2; ++ni)
                acc[mi][ni] = __builtin_amdgcn_mfma_f32_16x16x32_bf16(af[mi], bf[ni], acc[mi][ni], 0, 0, 0);
    }

    // epilogue: h/g -> swizzled LDS tiles (local [row][col], chunk XOR row&7)
    #pragma unroll
    for (int mi = 0; mi < 4; ++mi) {
        const int rowl = wm * 64 + mi * 16 + g * 4;
        #pragma unroll
        for (int ni = 0; ni < 2; ++ni) {
            const int coll = wn * 32 + ni * 16 + lr;
            const float bv = b1[bcol0 + coll];
            const int cc = coll >> 3, jj = coll & 7;
            #pragma unroll
            for (int r = 0; r < 4; ++r) {
                const int row = rowl + r;
                float h = tanh_fast(acc[mi][ni][r] + bv);
                int idx = row * 64 + ((cc ^ (row & 7)) << 3) + jj;
                hls[idx] = f2bf(h);
                gls[idx] = f2bf(1.f - h * h);
            }
        }
    }
    __syncthreads();

    // frag-ordered read + coalesced global store
    const int rt0 = arow0 >> 5, kk0 = bcol0 >> 4;
    #pragma unroll
    for (int i = 0; i < 4; ++i) {
        const int tile = (i * 256 + t) >> 6;       // 0..15
        const int ln = t & 63;
        const int rt = tile >> 2, kk = tile & 3;
        const int row = rt * 32 + (ln & 31);
        const int kb = kk * 16 + (ln >> 5) * 8;
        const int src = row * 64 + (((kb >> 3) ^ (row & 7)) << 3);
        const size_t dst = ((size_t)(rt0 + rt) * 64 + (kk0 + kk)) * 512 + ln * 8;
        *(s8v*)&h1f[dst] = *(const s8v*)&hls[src];
        *(s8v*)&g1f[dst] = *(const s8v*)&gls[src];
    }
}

// ---------------------------------------------------------------------------
// mid: fused dual GEMM, K=1024, tile 128x128, 4 waves 2x2 (wave 64x64),
// mfma_f32_32x32x16_bf16. NO LDS, NO BARRIERS: A (h1f/g1f) and B (W2Tf/VTf)
// all loaded as lane-linear fragment streams from L2.
//   C2 = h1@W2 -> h2f (fragment layout, bf16); T = g1@V -> trJ += rowsum(T*g2)
// ---------------------------------------------------------------------------
__launch_bounds__(256, 1)
__global__ void cnf_mid(const u16* __restrict__ h1f, const u16* __restrict__ g1f,
                        const u16* __restrict__ W2Tf, const u16* __restrict__ VTf,
                        const float* __restrict__ b2,
                        u16* __restrict__ h2f, float* __restrict__ trJ)
{
    const int t = threadIdx.x;
    const int wave = t >> 6, lane = t & 63;
    const int wm = wave >> 1, wn = wave & 1;
    const int arow0 = blockIdx.x * 128;
    const int ntb = blockIdx.y * 4;
    const int rt0 = (arow0 >> 5) + wm * 2;
    const int nt0 = ntb + wn * 2;

    const u16* pa1[2], *pa2[2], *pb1[2], *pb2[2];
    #pragma unroll
    for (int mi = 0; mi < 2; ++mi) {
        pa1[mi] = h1f + (size_t)(rt0 + mi) * 64 * 512 + lane * 8;
        pa2[mi] = g1f + (size_t)(rt0 + mi) * 64 * 512 + lane * 8;
    }
    #pragma unroll
    for (int ni = 0; ni < 2; ++ni) {
        pb1[ni] = W2Tf + (size_t)(nt0 + ni) * 64 * 512 + lane * 8;
        pb2[ni] = VTf  + (size_t)(nt0 + ni) * 64 * 512 + lane * 8;
    }

    f16v acc1[2][2], acc2[2][2];
    #pragma unroll
    for (int mi = 0; mi < 2; ++mi)
        #pragma unroll
        for (int ni = 0; ni < 2; ++ni)
            #pragma unroll
            for (int r = 0; r < 16; ++r) { acc1[mi][ni][r] = 0.f; acc2[mi][ni][r] = 0.f; }

    #pragma unroll 4
    for (int kk = 0; kk < 64; ++kk) {
        const size_t o = (size_t)kk * 512;
        s8v a1[2], a2[2], b1f[2], b2f[2];
        #pragma unroll
        for (int mi = 0; mi < 2; ++mi) {
            a1[mi] = *(const s8v*)(pa1[mi] + o);
            a2[mi] = *(const s8v*)(pa2[mi] + o);
        }
        #pragma unroll
        for (int ni = 0; ni < 2; ++ni) {
            b1f[ni] = *(const s8v*)(pb1[ni] + o);
            b2f[ni] = *(const s8v*)(pb2[ni] + o);
        }
        #pragma unroll
        for (int mi = 0; mi < 2; ++mi)
            #pragma unroll
            for (int ni = 0; ni < 2; ++ni) {
                acc1[mi][ni] = __builtin_amdgcn_mfma_f32_32x32x16_bf16(a1[mi], b1f[ni], acc1[mi][ni], 0, 0, 0);
                acc2[mi][ni] = __builtin_amdgcn_mfma_f32_32x32x16_bf16(a2[mi], b2f[ni], acc2[mi][ni], 0, 0, 0);
            }
    }

    // epilogue: h2 (frag layout) + trace reduction
    const int l31 = lane & 31, lh = lane >> 5;
    #pragma unroll
    for (int mi = 0; mi < 2; ++mi) {
        const int rt = (arow0 >> 5) + wm * 2 + mi;
        float tr[16];
        #pragma unroll
        for (int r = 0; r < 16; ++r) tr[r] = 0.f;
        #pragma unroll
        for (int ni = 0; ni < 2; ++ni) {
            const int q0 = (ntb + wn * 2 + ni) * 32;       // col base; col = q0 + l31
            const float bv = b2[q0 + l31];
            const size_t hb = (((size_t)rt * 64 + ((q0 + l31) >> 4)) * 64
                               + (((l31 >> 3) & 1) << 5)) * 8 + (l31 & 7) + lh * 32;
            #pragma unroll
            for (int r = 0; r < 16; ++r) {
                float hh = tanh_fast(acc1[mi][ni][r] + bv);
                float gg = 1.f - hh * hh;
                h2f[hb + ((r & 3) + ((r >> 2) << 3)) * 8] = f2bf(hh);
                tr[r] += acc2[mi][ni][r] * gg;
            }
        }
        #pragma unroll
        for (int off = 1; off < 32; off <<= 1)
            #pragma unroll
            for (int r = 0; r < 16; ++r) tr[r] += __shfl_xor(tr[r], off);
        if (l31 == 0) {
            const int rowb = arow0 + wm * 64 + mi * 32 + lh * 4;
            #pragma unroll
            for (int r = 0; r < 16; ++r)
                atomicAdd(&trJ[rowb + (r & 3) + ((r >> 2) << 3)], tr[r]);
        }
    }
}

// ---------------------------------------------------------------------------
// out: y = h2 @ W3 + b3 (fragment-direct, wave-split K, LDS reduce; no atomics)
// grid 128: 32-row tiles. out[:,0] = -trJ.
// ---------------------------------------------------------------------------
__launch_bounds__(256)
__global__ void cnf_out(const u16* __restrict__ h2f, const u16* __restrict__ W3Tf,
                        const float* __restrict__ b3, const float* __restrict__ trJ,
                        float* __restrict__ out)
{
    __shared__ float red[4][32][64];
    const int t = threadIdx.x;
    const int wave = t >> 6, lane = t & 63;
    const int rt = blockIdx.x;

    f16v acc[2];
    #pragma unroll
    for (int ni = 0; ni < 2; ++ni)
        #pragma unroll
        for (int r = 0; r < 16; ++r) acc[ni][r] = 0.f;

    #pragma unroll
    for (int kki = 0; kki < 16; ++kki) {
        const int kk = wave * 16 + kki;
        s8v af = *(const s8v*)&h2f[(((size_t)rt * 64 + kk) * 64 + lane) * 8];
        #pragma unroll
        for (int ni = 0; ni < 2; ++ni) {
            s8v bf = *(const s8v*)&W3Tf[(((size_t)ni * 64 + kk) * 64 + lane) * 8];
            acc[ni] = __builtin_amdgcn_mfma_f32_32x32x16_bf16(af, bf, acc[ni], 0, 0, 0);
        }
    }
    const int l31 = lane & 31, lh = lane >> 5;
    #pragma unroll
    for (int ni = 0; ni < 2; ++ni)
        #pragma unroll
        for (int r = 0; r < 16; ++r)
            red[wave][(r & 3) + ((r >> 2) << 3) + lh * 4][ni * 32 + l31] = acc[ni][r];
    __syncthreads();

    #pragma unroll
    for (int i = 0; i < 8; ++i) {
        int o = t * 8 + i;
        int row = o >> 6, col = o & 63;
        float s = red[0][row][col] + red[1][row][col] + red[2][row][col] + red[3][row][col] + b3[col];
        out[(size_t)(rt * 32 + row) * 65 + 1 + col] = s;
    }
    if (t < 32) out[(size_t)(rt * 32 + t) * 65] = -trJ[rt * 32 + t];
}

// ---------------------------------------------------------------------------
extern "C" void kernel_launch(void* const* d_in, const int* in_sizes, int n_in,
                              void* d_out, int out_size, void* d_ws, size_t ws_size,
                              hipStream_t stream) {
    const float* x  = (const float*)d_in[0];
    const float* W1 = (const float*)d_in[1];
    const float* b1 = (const float*)d_in[2];
    const float* W2 = (const float*)d_in[3];
    const float* b2 = (const float*)d_in[4];
    const float* W3 = (const float*)d_in[5];
    const float* b3 = (const float*)d_in[6];
    float* out = (float*)d_out;

    char* ws = (char*)d_ws;
    u16*   h1f = (u16*)(ws);                                  //  8 MB (frag layout)
    u16*   g1f = (u16*)(ws + (size_t)( 8u << 20));            //  8 MB (frag layout)
    u16*   h2f = (u16*)(ws + (size_t)(16u << 20));            //  8 MB (frag layout)
    u16*   W2T = (u16*)(ws + (size_t)(24u << 20));            //  2 MB (frag layout)
    u16*   VTb = (u16*)(ws + (size_t)(26u << 20));            //  2 MB (frag layout)
    float* trJ = (float*)(ws + (size_t)(28u << 20));          // 16 KB
    u16*   xbb = (u16*)(ws + (size_t)(28u << 20) + 65536);    // 512 KB
    u16*   W1T = (u16*)(ws + (size_t)(28u << 20) + 65536 + 524288);             // 128 KB
    u16*   W3T = (u16*)(ws + (size_t)(28u << 20) + 65536 + 524288 + 131072);    // 128 KB (frag)

    cnf_prep <<<dim3(32, 32), 256, 0, stream>>>(x, W1, W2, W3, W2T, VTb, xbb, W1T, W3T, trJ);
    cnf_gemm1<<<dim3(32, 16), 256, 0, stream>>>(xbb, W1T, b1, h1f, g1f);
    cnf_mid  <<<dim3(32, 8),  256, 0, stream>>>(h1f, g1f, W2T, VTb, b2, h2f, trJ);
    cnf_out  <<<128,          256, 0, stream>>>(h2f, W3T, b3, trJ, out);
}

// Round 8
// 61.543 us; speedup vs baseline: 1.0638x; 1.0638x over previous
//
#include <hip/hip_runtime.h>
#include <cmath>

typedef unsigned short u16;
typedef __attribute__((ext_vector_type(8))) short s8v;    // 8 bf16 (4 VGPRs)
typedef __attribute__((ext_vector_type(4))) float f4v;    // 16x16 acc / float4
typedef __attribute__((ext_vector_type(16))) float f16v;  // 32x32 acc

__device__ __forceinline__ u16 f2bf(float f) {
    union { float f; unsigned u; } v; v.f = f;
    unsigned r = v.u + 0x7FFFu + ((v.u >> 16) & 1u);   // RNE
    return (u16)(r >> 16);
}
// fast tanh: 1 - 2/(1+exp2(2x*log2e)); |err| ~1e-6
__device__ __forceinline__ float tanh_fast(float x) {
    float e = __builtin_amdgcn_exp2f(x * 2.88539008177792681f);
    return 1.f - 2.f * __builtin_amdgcn_rcpf(1.f + e);
}
// 16x16 subtile swizzled slot (gemm1 input staging; verified R5)
__device__ __forceinline__ int wslot(int row, int c) {
    return ((((c >> 2) << 6) | ((c & 3) << 4) | (row & 15)) ^ c);
}
// fragment-layout flat u16 index for element (n,k) of an n-major matrix (32x32 frag):
// lane = (n&31) + ((k>>3)&1)*32; j = k&7; tile (n>>5, k>>4)
__device__ __forceinline__ size_t fragoff(int n, int k) {
    return (((size_t)(n >> 5) * 64 + (k >> 4)) * 64 + (n & 31) + (((k >> 3) & 1) << 5)) * 8 + (k & 7);
}

// ---------------------------------------------------------------------------
// prep (grid 32x32, 256 thr):
//  all blocks : W2Tf[frag(n,k)]=bf16(W2[k][n]); VTf[frag(q,p)]=bf16(W2[p][q]*U[q][p]),
//               U = W3 @ W1 ; xb = bf16(x[:,1:])
//  by==0      : W1T[p][i] bf16 row-major; zero trJ
//  by==1      : W3Tf[frag(n,k)] = bf16(W3[k][n])
// ---------------------------------------------------------------------------
__launch_bounds__(256)
__global__ void cnf_prep(const float* __restrict__ x, const float* __restrict__ W1,
                         const float* __restrict__ W2, const float* __restrict__ W3,
                         u16* __restrict__ W2Tf, u16* __restrict__ VTf,
                         u16* __restrict__ xb, u16* __restrict__ W1T,
                         u16* __restrict__ W3Tf, float* __restrict__ trJ)
{
    __shared__ float w2s[32][33];
    __shared__ float w1s[64][33];    // [i][p] transposed: conflict-free col reads
    const int a = blockIdx.x * 32;   // p / k (rows of W2)
    const int b = blockIdx.y * 32;   // q / n (cols of W2)
    const int t = threadIdx.x;

    #pragma unroll
    for (int it = 0; it < 4; ++it) {
        int idx = t + it * 256;
        w2s[idx >> 5][idx & 31] = W2[(a + (idx >> 5)) * 1024 + b + (idx & 31)];
    }
    #pragma unroll
    for (int it = 0; it < 8; ++it) {
        int idx = t + it * 256;
        w1s[idx >> 5][idx & 31] = W1[(idx >> 5) * 1024 + a + (idx & 31)];
    }
    __syncthreads();

    #pragma unroll
    for (int it = 0; it < 4; ++it) {
        int idx = t + it * 256;
        int rr = idx >> 5, cc = idx & 31;
        W2Tf[fragoff(b + rr, a + cc)] = f2bf(w2s[cc][rr]);
    }
    #pragma unroll
    for (int it = 0; it < 4; ++it) {
        int idx = t + it * 256;
        int qq = idx >> 5, pp = idx & 31;
        const float* w3row = W3 + (b + qq) * 64;
        float u = 0.f;
        #pragma unroll
        for (int i4 = 0; i4 < 16; ++i4) {
            f4v w3v = *(const f4v*)&w3row[i4 * 4];
            u += w3v[0] * w1s[i4 * 4 + 0][pp] + w3v[1] * w1s[i4 * 4 + 1][pp]
               + w3v[2] * w1s[i4 * 4 + 2][pp] + w3v[3] * w1s[i4 * 4 + 3][pp];
        }
        VTf[fragoff(b + qq, a + pp)] = f2bf(w2s[pp][qq] * u);
    }
    {
        int bid = blockIdx.y * 32 + blockIdx.x;
        int e = bid * 256 + t;
        xb[e] = f2bf(x[(e >> 6) * 65 + 1 + (e & 63)]);
    }
    if (blockIdx.y == 0) {
        int pp = t >> 3, i0 = (t & 7) * 8;
        s8v v;
        #pragma unroll
        for (int j = 0; j < 8; ++j) v[j] = (short)f2bf(w1s[i0 + j][pp]);
        *(s8v*)&W1T[(a + pp) * 64 + i0] = v;
        if (t < 128) trJ[blockIdx.x * 128 + t] = 0.f;
    }
    if (blockIdx.y == 1) {
        int idx = blockIdx.x * 256 + t;
        int n = idx & 63, k0 = (idx >> 6) * 8;
        s8v v;
        #pragma unroll
        for (int j = 0; j < 8; ++j) v[j] = (short)f2bf(W3[(k0 + j) * 64 + n]);
        *(s8v*)&W3Tf[fragoff(n, k0)] = v;
    }
}

// ---------------------------------------------------------------------------
// gemm1 (MFMA 16x16x32): h1 = tanh(xb @ W1T^T + b1), g1 = 1-h1^2 (ROW-MAJOR out)
// Coalesced stores via swizzled LDS transpose tiles (R7 technique, row-major dst).
// Block 128 rows x 64 cols, grid (32,16), 4 waves 2x2.
// ---------------------------------------------------------------------------
__launch_bounds__(256)
__global__ void cnf_gemm1(const u16* __restrict__ xb, const u16* __restrict__ W1T,
                          const float* __restrict__ b1,
                          u16* __restrict__ h1, u16* __restrict__ g1)
{
    __shared__ __align__(16) u16 lds[12 * 1024];   // 24 KB input staging
    __shared__ __align__(16) u16 hls[128 * 64];    // 16 KB
    __shared__ __align__(16) u16 gls[128 * 64];    // 16 KB
    const int t = threadIdx.x;
    const int wave = t >> 6, lane = t & 63;
    const int wm = wave >> 1, wn = wave & 1;
    const int g = lane >> 4, lr = lane & 15;
    const int arow0 = blockIdx.x * 128, bcol0 = blockIdx.y * 64;

    #pragma unroll
    for (int i = 0; i < 4; ++i) {
        int ch = t + i * 256, row = ch >> 3, c = ch & 7;
        *(s8v*)&lds[(row >> 4) * 1024 + wslot(row, c) * 8] =
            *(const s8v*)&xb[(arow0 + row) * 64 + c * 8];
    }
    #pragma unroll
    for (int i = 0; i < 2; ++i) {
        int ch = t + i * 256, row = ch >> 3, c = ch & 7;
        *(s8v*)&lds[(8 + (row >> 4)) * 1024 + wslot(row, c) * 8] =
            *(const s8v*)&W1T[(bcol0 + row) * 64 + c * 8];
    }
    __syncthreads();

    f4v acc[4][2];
    #pragma unroll
    for (int mi = 0; mi < 4; ++mi)
        #pragma unroll
        for (int ni = 0; ni < 2; ++ni) acc[mi][ni] = f4v{0.f,0.f,0.f,0.f};

    #pragma unroll
    for (int ks = 0; ks < 2; ++ks) {
        const int lo = (ks * 64 + (lane ^ ((ks * 4 + g) & 7))) * 8;
        s8v af[4], bf[2];
        #pragma unroll
        for (int mi = 0; mi < 4; ++mi) af[mi] = *(const s8v*)&lds[(wm * 4 + mi) * 1024 + lo];
        #pragma unroll
        for (int ni = 0; ni < 2; ++ni) bf[ni] = *(const s8v*)&lds[(8 + wn * 2 + ni) * 1024 + lo];
        #pragma unroll
        for (int mi = 0; mi < 4; ++mi)
            #pragma unroll
            for (int ni = 0; ni < 2; ++ni)
                acc[mi][ni] = __builtin_amdgcn_mfma_f32_16x16x32_bf16(af[mi], bf[ni], acc[mi][ni], 0, 0, 0);
    }

    // epilogue: h/g -> swizzled LDS tiles [row][col] (8-col chunk XOR row&7)
    #pragma unroll
    for (int mi = 0; mi < 4; ++mi) {
        const int rowl = wm * 64 + mi * 16 + g * 4;
        #pragma unroll
        for (int ni = 0; ni < 2; ++ni) {
            const int coll = wn * 32 + ni * 16 + lr;
            const float bv = b1[bcol0 + coll];
            const int cc = coll >> 3, jj = coll & 7;
            #pragma unroll
            for (int r = 0; r < 4; ++r) {
                const int row = rowl + r;
                float h = tanh_fast(acc[mi][ni][r] + bv);
                int idx = row * 64 + ((cc ^ (row & 7)) << 3) + jj;
                hls[idx] = f2bf(h);
                gls[idx] = f2bf(1.f - h * h);
            }
        }
    }
    __syncthreads();

    // coalesced row-major global stores
    #pragma unroll
    for (int i = 0; i < 4; ++i) {
        int id = i * 256 + t;
        int row = id >> 3, ch = id & 7;
        int src = row * 64 + ((ch ^ (row & 7)) << 3);
        size_t dst = (size_t)(arow0 + row) * 1024 + bcol0 + ch * 8;
        *(s8v*)&h1[dst] = *(const s8v*)&hls[src];
        *(s8v*)&g1[dst] = *(const s8v*)&gls[src];
    }
}

// ---------------------------------------------------------------------------
// mid: fused dual GEMM, K=1024, tile 128x128, 8 waves (512 thr), wave 32x64,
// mfma_f32_32x32x16_bf16, 2 waves/SIMD. A (h1,g1 row-major) via LDS ping-pong
// (1 barrier/kt, swizzled); B (W2Tf,VTf) direct global frag loads, dbuf 1 ahead.
//   C2 = h1@W2 -> h2f (frag layout); T = g1@V -> trJ += rowsum(T*g2)
// ---------------------------------------------------------------------------
#define LOADA(dh, dg, ko) \
    do { dh = *(const s8v*)(h1p + (ko)); dg = *(const s8v*)(g1p + (ko)); } while (0)

#define LOADB(B, kkg)                                                          \
    do { _Pragma("unroll")                                                     \
         for (int _ks = 0; _ks < 2; ++_ks)                                     \
         _Pragma("unroll")                                                     \
         for (int _ni = 0; _ni < 2; ++_ni) {                                   \
             size_t _o = (((size_t)(nt0 + _ni) * 64 + (kkg) * 2 + _ks) * 64 + lane) * 8; \
             B[_ks*4 + _ni*2 + 0] = *(const s8v*)&W2Tf[_o];                    \
             B[_ks*4 + _ni*2 + 1] = *(const s8v*)&VTf[_o];                     \
         } } while (0)

#define WRITEA(sh, sg, bb)                                                     \
    do { u16* _wb = &lds[bb][0];                                               \
         *(s8v*)&_wb[sdst] = sh; *(s8v*)&_wb[4096 + sdst] = sg; } while (0)

#define MIDBODY(kt, AwH, AwG, AlH, AlG, Bc, Bn)                                \
    {                                                                          \
        if ((kt) < 30) { const int _ko = ((kt) + 2) * 32; LOADA(AlH, AlG, _ko); } \
        if ((kt) < 31) { WRITEA(AwH, AwG, ((kt) + 1) & 1); LOADB(Bn, (kt) + 1); } \
        const u16* buf = &lds[(kt) & 1][0];                                    \
        _Pragma("unroll")                                                      \
        for (int ks = 0; ks < 2; ++ks) {                                       \
            const int lp = (lane ^ ((lane >> 5) << 2) ^ (ks << 1)) * 8;        \
            const int R = wrt * 2 + ks;                                        \
            s8v a1 = *(const s8v*)&buf[R * 512 + lp];                          \
            s8v a2 = *(const s8v*)&buf[4096 + R * 512 + lp];                   \
            _Pragma("unroll")                                                  \
            for (int ni = 0; ni < 2; ++ni) {                                   \
                acc1[ni] = __builtin_amdgcn_mfma_f32_32x32x16_bf16(a1, Bc[ks*4+ni*2+0], acc1[ni], 0, 0, 0); \
                acc2[ni] = __builtin_amdgcn_mfma_f32_32x32x16_bf16(a2, Bc[ks*4+ni*2+1], acc2[ni], 0, 0, 0); \
            }                                                                  \
        }                                                                      \
        __syncthreads();                                                       \
    }

__launch_bounds__(512, 2)
__global__ void cnf_mid(const u16* __restrict__ h1, const u16* __restrict__ g1,
                        const u16* __restrict__ W2Tf, const u16* __restrict__ VTf,
                        const float* __restrict__ b2,
                        u16* __restrict__ h2f, float* __restrict__ trJ)
{
    __shared__ __align__(16) u16 lds[2][8192];   // 2 x 16 KiB

    const int t = threadIdx.x;
    const int wave = t >> 6, lane = t & 63;
    const int wrt = wave & 3;          // row-tile 0..3 (32 rows each)
    const int wn  = wave >> 2;         // col half 0..1
    const int arow0 = blockIdx.x * 128;
    const int ntb = blockIdx.y * 4;
    const int nt0 = ntb + wn * 2;      // this wave's 2 col-tiles

    // staging: 1 chunk/thread/matrix; chunk = (row = t>>2, kc = t&3)
    const int row = t >> 2, c = t & 3;
    const int R0 = (row >> 5) * 2 + (c >> 1);
    const int L0 = (row & 31) + ((c & 1) << 5);
    const int sdst = (R0 * 64 + (L0 ^ ((L0 >> 5) << 2) ^ ((R0 & 1) << 1))) * 8;
    const u16* h1p = h1 + (size_t)(arow0 + row) * 1024 + c * 8;
    const u16* g1p = g1 + (size_t)(arow0 + row) * 1024 + c * 8;

    f16v acc1[2], acc2[2];
    #pragma unroll
    for (int ni = 0; ni < 2; ++ni)
        #pragma unroll
        for (int r = 0; r < 16; ++r) { acc1[ni][r] = 0.f; acc2[ni][r] = 0.f; }

    s8v ahA, agA, ahB, agB;
    s8v bA[8], bB[8];

    LOADA(ahA, agA, 0);                // A(0)
    WRITEA(ahA, agA, 0);               // -> lds[0]
    LOADA(ahB, agB, 32);               // A(1)
    LOADB(bA, 0);                      // B(0)
    __syncthreads();

    for (int kt2 = 0; kt2 < 16; ++kt2) {
        const int kt = kt2 * 2;
        MIDBODY(kt,     ahB, agB, ahA, agA, bA, bB);
        MIDBODY(kt + 1, ahA, agA, ahB, agB, bB, bA);
    }

    // epilogue: h2 (frag layout) + trace reduction
    const int l31 = lane & 31, lh = lane >> 5;
    const int rt = (arow0 >> 5) + wrt;
    float tr[16];
    #pragma unroll
    for (int r = 0; r < 16; ++r) tr[r] = 0.f;
    #pragma unroll
    for (int ni = 0; ni < 2; ++ni) {
        const int q0 = (nt0 + ni) * 32;            // col base; col = q0 + l31
        const float bv = b2[q0 + l31];
        const size_t hb = (((size_t)rt * 64 + ((q0 + l31) >> 4)) * 64
                           + (((l31 >> 3) & 1) << 5)) * 8 + (l31 & 7) + lh * 32;
        #pragma unroll
        for (int r = 0; r < 16; ++r) {
            float hh = tanh_fast(acc1[ni][r] + bv);
            float gg = 1.f - hh * hh;
            h2f[hb + ((r & 3) + ((r >> 2) << 3)) * 8] = f2bf(hh);
            tr[r] += acc2[ni][r] * gg;
        }
    }
    #pragma unroll
    for (int off = 1; off < 32; off <<= 1)
        #pragma unroll
        for (int r = 0; r < 16; ++r) tr[r] += __shfl_xor(tr[r], off);
    if (l31 == 0) {
        const int rowb = arow0 + wrt * 32 + lh * 4;
        #pragma unroll
        for (int r = 0; r < 16; ++r)
            atomicAdd(&trJ[rowb + (r & 3) + ((r >> 2) << 3)], tr[r]);
    }
}

// ---------------------------------------------------------------------------
// out: y = h2 @ W3 + b3 (fragment-direct, wave-split K, LDS reduce; no atomics)
// grid 128: 32-row tiles. out[:,0] = -trJ.
// ---------------------------------------------------------------------------
__launch_bounds__(256)
__global__ void cnf_out(const u16* __restrict__ h2f, const u16* __restrict__ W3Tf,
                        const float* __restrict__ b3, const float* __restrict__ trJ,
                        float* __restrict__ out)
{
    __shared__ float red[4][32][64];
    const int t = threadIdx.x;
    const int wave = t >> 6, lane = t & 63;
    const int rt = blockIdx.x;

    f16v acc[2];
    #pragma unroll
    for (int ni = 0; ni < 2; ++ni)
        #pragma unroll
        for (int r = 0; r < 16; ++r) acc[ni][r] = 0.f;

    #pragma unroll
    for (int kki = 0; kki < 16; ++kki) {
        const int kk = wave * 16 + kki;
        s8v af = *(const s8v*)&h2f[(((size_t)rt * 64 + kk) * 64 + lane) * 8];
        #pragma unroll
        for (int ni = 0; ni < 2; ++ni) {
            s8v bf = *(const s8v*)&W3Tf[(((size_t)ni * 64 + kk) * 64 + lane) * 8];
            acc[ni] = __builtin_amdgcn_mfma_f32_32x32x16_bf16(af, bf, acc[ni], 0, 0, 0);
        }
    }
    const int l31 = lane & 31, lh = lane >> 5;
    #pragma unroll
    for (int ni = 0; ni < 2; ++ni)
        #pragma unroll
        for (int r = 0; r < 16; ++r)
            red[wave][(r & 3) + ((r >> 2) << 3) + lh * 4][ni * 32 + l31] = acc[ni][r];
    __syncthreads();

    #pragma unroll
    for (int i = 0; i < 8; ++i) {
        int o = t * 8 + i;
        int row = o >> 6, col = o & 63;
        float s = red[0][row][col] + red[1][row][col] + red[2][row][col] + red[3][row][col] + b3[col];
        out[(size_t)(rt * 32 + row) * 65 + 1 + col] = s;
    }
    if (t < 32) out[(size_t)(rt * 32 + t) * 65] = -trJ[rt * 32 + t];
}

// ---------------------------------------------------------------------------
extern "C" void kernel_launch(void* const* d_in, const int* in_sizes, int n_in,
                              void* d_out, int out_size, void* d_ws, size_t ws_size,
                              hipStream_t stream) {
    const float* x  = (const float*)d_in[0];
    const float* W1 = (const float*)d_in[1];
    const float* b1 = (const float*)d_in[2];
    const float* W2 = (const float*)d_in[3];
    const float* b2 = (const float*)d_in[4];
    const float* W3 = (const float*)d_in[5];
    const float* b3 = (const float*)d_in[6];
    float* out = (float*)d_out;

    char* ws = (char*)d_ws;
    u16*   h1b = (u16*)(ws);                                  //  8 MB (row-major)
    u16*   g1b = (u16*)(ws + (size_t)( 8u << 20));            //  8 MB (row-major)
    u16*   h2f = (u16*)(ws + (size_t)(16u << 20));            //  8 MB (frag layout)
    u16*   W2T = (u16*)(ws + (size_t)(24u << 20));            //  2 MB (frag layout)
    u16*   VTb = (u16*)(ws + (size_t)(26u << 20));            //  2 MB (frag layout)
    float* trJ = (float*)(ws + (size_t)(28u << 20));          // 16 KB
    u16*   xbb = (u16*)(ws + (size_t)(28u << 20) + 65536);    // 512 KB
    u16*   W1T = (u16*)(ws + (size_t)(28u << 20) + 65536 + 524288);             // 128 KB
    u16*   W3T = (u16*)(ws + (size_t)(28u << 20) + 65536 + 524288 + 131072);    // 128 KB (frag)

    cnf_prep <<<dim3(32, 32), 256, 0, stream>>>(x, W1, W2, W3, W2T, VTb, xbb, W1T, W3T, trJ);
    cnf_gemm1<<<dim3(32, 16), 256, 0, stream>>>(xbb, W1T, b1, h1b, g1b);
    cnf_mid  <<<dim3(32, 8),  512, 0, stream>>>(h1b, g1b, W2T, VTb, b2, h2f, trJ);
    cnf_out  <<<128,          256, 0, stream>>>(h2f, W3T, b3, trJ, out);
}

// Round 9
// 55.494 us; speedup vs baseline: 1.1797x; 1.1090x over previous
//
#include <hip/hip_runtime.h>
#include <cmath>

typedef unsigned short u16;
typedef __attribute__((ext_vector_type(8))) short s8v;    // 8 bf16 (4 VGPRs)
typedef __attribute__((ext_vector_type(4))) float f4v;    // 16x16 acc / float4
typedef __attribute__((ext_vector_type(16))) float f16v;  // 32x32 acc

__device__ __forceinline__ u16 f2bf(float f) {
    union { float f; unsigned u; } v; v.f = f;
    unsigned r = v.u + 0x7FFFu + ((v.u >> 16) & 1u);   // RNE
    return (u16)(r >> 16);
}
// fast tanh: 1 - 2/(1+exp2(2x*log2e)); |err| ~1e-6
__device__ __forceinline__ float tanh_fast(float x) {
    float e = __builtin_amdgcn_exp2f(x * 2.88539008177792681f);
    return 1.f - 2.f * __builtin_amdgcn_rcpf(1.f + e);
}
// 16x16 subtile swizzled slot (gemm1 input staging; verified R5)
__device__ __forceinline__ int wslot(int row, int c) {
    return ((((c >> 2) << 6) | ((c & 3) << 4) | (row & 15)) ^ c);
}
// fragment-layout flat u16 index for element (n,k) of an n-major matrix (32x32 frag):
// lane = (n&31) + ((k>>3)&1)*32; j = k&7; tile (n>>5, k>>4)
__device__ __forceinline__ size_t fragoff(int n, int k) {
    return (((size_t)(n >> 5) * 64 + (k >> 4)) * 64 + (n & 31) + (((k >> 3) & 1) << 5)) * 8 + (k & 7);
}

// ---------------------------------------------------------------------------
// prep (grid 32x32, 256 thr):
//  all blocks : W2Tf[frag(n,k)]=bf16(W2[k][n]); VTf[frag(q,p)]=bf16(W2[p][q]*U[q][p]),
//               U = W3 @ W1 (f4v-vectorized, broadcast-friendly LDS reads);
//               xb = bf16(x[:,1:])
//  by==0      : W1T[p][i] bf16 row-major; zero trJ
//  by==1      : W3Tf[frag(n,k)] = bf16(W3[k][n])
// ---------------------------------------------------------------------------
__launch_bounds__(256)
__global__ void cnf_prep(const float* __restrict__ x, const float* __restrict__ W1,
                         const float* __restrict__ W2, const float* __restrict__ W3,
                         u16* __restrict__ W2Tf, u16* __restrict__ VTf,
                         u16* __restrict__ xb, u16* __restrict__ W1T,
                         u16* __restrict__ W3Tf, float* __restrict__ trJ)
{
    __shared__ float w2s[32][33];
    __shared__ __align__(16) float w1s[64][36];   // [i][p], 16B-aligned rows
    const int a = blockIdx.x * 32;   // p / k (rows of W2)
    const int b = blockIdx.y * 32;   // q / n (cols of W2)
    const int t = threadIdx.x;

    #pragma unroll
    for (int it = 0; it < 4; ++it) {
        int idx = t + it * 256;
        w2s[idx >> 5][idx & 31] = W2[(a + (idx >> 5)) * 1024 + b + (idx & 31)];
    }
    #pragma unroll
    for (int it = 0; it < 8; ++it) {
        int idx = t + it * 256;
        w1s[idx >> 5][idx & 31] = W1[(idx >> 5) * 1024 + a + (idx & 31)];
    }
    __syncthreads();

    #pragma unroll
    for (int it = 0; it < 4; ++it) {
        int idx = t + it * 256;
        int rr = idx >> 5, cc = idx & 31;
        W2Tf[fragoff(b + rr, a + cc)] = f2bf(w2s[cc][rr]);
    }
    // U-loop: thread = (q = t>>3, pg = t&7) computes u[j] for p = pg*4+j.
    // w1s f4v reads: 8 distinct 16B addrs/wave (bank-disjoint), 8-way broadcast.
    {
        const int q = t >> 3, pg = t & 7;
        const float* w3row = W3 + (b + q) * 64;
        f4v u = f4v{0.f, 0.f, 0.f, 0.f};
        #pragma unroll
        for (int i4 = 0; i4 < 16; ++i4) {
            f4v w3v = *(const f4v*)&w3row[i4 * 4];
            #pragma unroll
            for (int s = 0; s < 4; ++s) {
                f4v wv = *(const f4v*)&w1s[i4 * 4 + s][pg * 4];
                u += w3v[s] * wv;
            }
        }
        #pragma unroll
        for (int j = 0; j < 4; ++j) {
            const int pp = pg * 4 + j;
            VTf[fragoff(b + q, a + pp)] = f2bf(w2s[pp][q] * u[j]);
        }
    }
    {
        int bid = blockIdx.y * 32 + blockIdx.x;
        int e = bid * 256 + t;
        xb[e] = f2bf(x[(e >> 6) * 65 + 1 + (e & 63)]);
    }
    if (blockIdx.y == 0) {
        int pp = t >> 3, i0 = (t & 7) * 8;
        s8v v;
        #pragma unroll
        for (int j = 0; j < 8; ++j) v[j] = (short)f2bf(w1s[i0 + j][pp]);
        *(s8v*)&W1T[(a + pp) * 64 + i0] = v;
        if (t < 128) trJ[blockIdx.x * 128 + t] = 0.f;
    }
    if (blockIdx.y == 1) {
        int idx = blockIdx.x * 256 + t;
        int n = idx & 63, k0 = (idx >> 6) * 8;
        s8v v;
        #pragma unroll
        for (int j = 0; j < 8; ++j) v[j] = (short)f2bf(W3[(k0 + j) * 64 + n]);
        *(s8v*)&W3Tf[fragoff(n, k0)] = v;
    }
}

// ---------------------------------------------------------------------------
// gemm1 (MFMA 16x16x32): h1 = tanh(xb @ W1T^T + b1), g1 = 1-h1^2 (ROW-MAJOR out)
// Coalesced stores via swizzled LDS transpose tiles.
// ---------------------------------------------------------------------------
__launch_bounds__(256)
__global__ void cnf_gemm1(const u16* __restrict__ xb, const u16* __restrict__ W1T,
                          const float* __restrict__ b1,
                          u16* __restrict__ h1, u16* __restrict__ g1)
{
    __shared__ __align__(16) u16 lds[12 * 1024];   // 24 KB input staging
    __shared__ __align__(16) u16 hls[128 * 64];    // 16 KB
    __shared__ __align__(16) u16 gls[128 * 64];    // 16 KB
    const int t = threadIdx.x;
    const int wave = t >> 6, lane = t & 63;
    const int wm = wave >> 1, wn = wave & 1;
    const int g = lane >> 4, lr = lane & 15;
    const int arow0 = blockIdx.x * 128, bcol0 = blockIdx.y * 64;

    #pragma unroll
    for (int i = 0; i < 4; ++i) {
        int ch = t + i * 256, row = ch >> 3, c = ch & 7;
        *(s8v*)&lds[(row >> 4) * 1024 + wslot(row, c) * 8] =
            *(const s8v*)&xb[(arow0 + row) * 64 + c * 8];
    }
    #pragma unroll
    for (int i = 0; i < 2; ++i) {
        int ch = t + i * 256, row = ch >> 3, c = ch & 7;
        *(s8v*)&lds[(8 + (row >> 4)) * 1024 + wslot(row, c) * 8] =
            *(const s8v*)&W1T[(bcol0 + row) * 64 + c * 8];
    }
    __syncthreads();

    f4v acc[4][2];
    #pragma unroll
    for (int mi = 0; mi < 4; ++mi)
        #pragma unroll
        for (int ni = 0; ni < 2; ++ni) acc[mi][ni] = f4v{0.f,0.f,0.f,0.f};

    #pragma unroll
    for (int ks = 0; ks < 2; ++ks) {
        const int lo = (ks * 64 + (lane ^ ((ks * 4 + g) & 7))) * 8;
        s8v af[4], bf[2];
        #pragma unroll
        for (int mi = 0; mi < 4; ++mi) af[mi] = *(const s8v*)&lds[(wm * 4 + mi) * 1024 + lo];
        #pragma unroll
        for (int ni = 0; ni < 2; ++ni) bf[ni] = *(const s8v*)&lds[(8 + wn * 2 + ni) * 1024 + lo];
        #pragma unroll
        for (int mi = 0; mi < 4; ++mi)
            #pragma unroll
            for (int ni = 0; ni < 2; ++ni)
                acc[mi][ni] = __builtin_amdgcn_mfma_f32_16x16x32_bf16(af[mi], bf[ni], acc[mi][ni], 0, 0, 0);
    }

    #pragma unroll
    for (int mi = 0; mi < 4; ++mi) {
        const int rowl = wm * 64 + mi * 16 + g * 4;
        #pragma unroll
        for (int ni = 0; ni < 2; ++ni) {
            const int coll = wn * 32 + ni * 16 + lr;
            const float bv = b1[bcol0 + coll];
            const int cc = coll >> 3, jj = coll & 7;
            #pragma unroll
            for (int r = 0; r < 4; ++r) {
                const int row = rowl + r;
                float h = tanh_fast(acc[mi][ni][r] + bv);
                int idx = row * 64 + ((cc ^ (row & 7)) << 3) + jj;
                hls[idx] = f2bf(h);
                gls[idx] = f2bf(1.f - h * h);
            }
        }
    }
    __syncthreads();

    #pragma unroll
    for (int i = 0; i < 4; ++i) {
        int id = i * 256 + t;
        int row = id >> 3, ch = id & 7;
        int src = row * 64 + ((ch ^ (row & 7)) << 3);
        size_t dst = (size_t)(arow0 + row) * 1024 + bcol0 + ch * 8;
        *(s8v*)&h1[dst] = *(const s8v*)&hls[src];
        *(s8v*)&g1[dst] = *(const s8v*)&gls[src];
    }
}

// ---------------------------------------------------------------------------
// mid: fused dual GEMM, K=1024, tile 128x128, 8 waves (512 thr),
// WAVE TILE 64x32 (wrt=wave&1 row-half, wn=wave>>1 col-quarter):
// halves per-wave B-frag loads (4/kt) -> B L2 traffic 512->256 MB.
// mfma_f32_32x32x16_bf16. A via LDS ping-pong (1 barrier/kt, swizzled);
// B (W2Tf,VTf) direct global frag loads, dbuf 1 kt ahead.
//   C2 = h1@W2 -> h2f (frag layout); T = g1@V -> trJ += rowsum(T*g2)
// ---------------------------------------------------------------------------
#define LOADA(dh, dg, ko) \
    do { dh = *(const s8v*)(h1p + (ko)); dg = *(const s8v*)(g1p + (ko)); } while (0)

#define LOADB(B, kkg)                                                          \
    do { _Pragma("unroll")                                                     \
         for (int _ks = 0; _ks < 2; ++_ks) {                                   \
             size_t _o = (((size_t)(ntb + wn) * 64 + (kkg) * 2 + _ks) * 64 + lane) * 8; \
             B[_ks*2 + 0] = *(const s8v*)&W2Tf[_o];                            \
             B[_ks*2 + 1] = *(const s8v*)&VTf[_o];                             \
         } } while (0)

#define WRITEA(sh, sg, bb)                                                     \
    do { u16* _wb = &lds[bb][0];                                               \
         *(s8v*)&_wb[sdst] = sh; *(s8v*)&_wb[4096 + sdst] = sg; } while (0)

#define MIDBODY(kt, AwH, AwG, AlH, AlG, Bc, Bn)                                \
    {                                                                          \
        if ((kt) < 30) { const int _ko = ((kt) + 2) * 32; LOADA(AlH, AlG, _ko); } \
        if ((kt) < 31) { WRITEA(AwH, AwG, ((kt) + 1) & 1); LOADB(Bn, (kt) + 1); } \
        const u16* buf = &lds[(kt) & 1][0];                                    \
        _Pragma("unroll")                                                      \
        for (int ks = 0; ks < 2; ++ks) {                                       \
            const int lp = (lane ^ ((lane >> 5) << 2) ^ (ks << 1)) * 8;        \
            s8v a1[2], a2[2];                                                  \
            _Pragma("unroll")                                                  \
            for (int mt = 0; mt < 2; ++mt) {                                   \
                const int R = (wrt * 2 + mt) * 2 + ks;                         \
                a1[mt] = *(const s8v*)&buf[R * 512 + lp];                      \
                a2[mt] = *(const s8v*)&buf[4096 + R * 512 + lp];               \
            }                                                                  \
            _Pragma("unroll")                                                  \
            for (int mt = 0; mt < 2; ++mt) {                                   \
                acc1[mt] = __builtin_amdgcn_mfma_f32_32x32x16_bf16(a1[mt], Bc[ks*2+0], acc1[mt], 0, 0, 0); \
                acc2[mt] = __builtin_amdgcn_mfma_f32_32x32x16_bf16(a2[mt], Bc[ks*2+1], acc2[mt], 0, 0, 0); \
            }                                                                  \
        }                                                                      \
        __syncthreads();                                                       \
    }

__launch_bounds__(512, 1)
__global__ void cnf_mid(const u16* __restrict__ h1, const u16* __restrict__ g1,
                        const u16* __restrict__ W2Tf, const u16* __restrict__ VTf,
                        const float* __restrict__ b2,
                        u16* __restrict__ h2f, float* __restrict__ trJ)
{
    __shared__ __align__(16) u16 lds[2][8192];   // 2 x 16 KiB (A only)

    const int t = threadIdx.x;
    const int wave = t >> 6, lane = t & 63;
    const int wrt = wave & 1;          // row half (64 rows = 2 mtiles)
    const int wn  = wave >> 1;         // col quarter (32 cols = 1 ntile)
    const int arow0 = blockIdx.x * 128;
    const int ntb = blockIdx.y * 4;

    // A staging: 1 chunk/thread/matrix; chunk = (row = t>>2, kc = t&3)
    const int row = t >> 2, c = t & 3;
    const int R0 = (row >> 5) * 2 + (c >> 1);
    const int L0 = (row & 31) + ((c & 1) << 5);
    const int sdst = (R0 * 64 + (L0 ^ ((L0 >> 5) << 2) ^ ((R0 & 1) << 1))) * 8;
    const u16* h1p = h1 + (size_t)(arow0 + row) * 1024 + c * 8;
    const u16* g1p = g1 + (size_t)(arow0 + row) * 1024 + c * 8;

    f16v acc1[2], acc2[2];
    #pragma unroll
    for (int mt = 0; mt < 2; ++mt)
        #pragma unroll
        for (int r = 0; r < 16; ++r) { acc1[mt][r] = 0.f; acc2[mt][r] = 0.f; }

    s8v ahA, agA, ahB, agB;
    s8v bA[4], bB[4];

    LOADA(ahA, agA, 0);                // A(0)
    WRITEA(ahA, agA, 0);               // -> lds[0]
    LOADA(ahB, agB, 32);               // A(1)
    LOADB(bA, 0);                      // B(0)
    __syncthreads();

    for (int kt2 = 0; kt2 < 16; ++kt2) {
        const int kt = kt2 * 2;
        MIDBODY(kt,     ahB, agB, ahA, agA, bA, bB);
        MIDBODY(kt + 1, ahA, agA, ahB, agB, bB, bA);
    }

    // epilogue: h2 (frag layout) + trace reduction
    const int l31 = lane & 31, lh = lane >> 5;
    #pragma unroll
    for (int mt = 0; mt < 2; ++mt) {
        const int rt = (arow0 >> 5) + wrt * 2 + mt;
        const int q0 = (ntb + wn) * 32;            // col base; col = q0 + l31
        const float bv = b2[q0 + l31];
        const size_t hb = (((size_t)rt * 64 + ((q0 + l31) >> 4)) * 64
                           + (((l31 >> 3) & 1) << 5)) * 8 + (l31 & 7) + lh * 32;
        float tr[16];
        #pragma unroll
        for (int r = 0; r < 16; ++r) {
            float hh = tanh_fast(acc1[mt][r] + bv);
            float gg = 1.f - hh * hh;
            h2f[hb + ((r & 3) + ((r >> 2) << 3)) * 8] = f2bf(hh);
            tr[r] = acc2[mt][r] * gg;
        }
        #pragma unroll
        for (int off = 1; off < 32; off <<= 1)
            #pragma unroll
            for (int r = 0; r < 16; ++r) tr[r] += __shfl_xor(tr[r], off);
        if (l31 == 0) {
            const int rowb = arow0 + (wrt * 2 + mt) * 32 + lh * 4;
            #pragma unroll
            for (int r = 0; r < 16; ++r)
                atomicAdd(&trJ[rowb + (r & 3) + ((r >> 2) << 3)], tr[r]);
        }
    }
}

// ---------------------------------------------------------------------------
// out: y = h2 @ W3 + b3 (fragment-direct, wave-split K, LDS reduce; no atomics)
// grid 128: 32-row tiles. out[:,0] = -trJ.
// ---------------------------------------------------------------------------
__launch_bounds__(256)
__global__ void cnf_out(const u16* __restrict__ h2f, const u16* __restrict__ W3Tf,
                        const float* __restrict__ b3, const float* __restrict__ trJ,
                        float* __restrict__ out)
{
    __shared__ float red[4][32][64];
    const int t = threadIdx.x;
    const int wave = t >> 6, lane = t & 63;
    const int rt = blockIdx.x;

    f16v acc[2];
    #pragma unroll
    for (int ni = 0; ni < 2; ++ni)
        #pragma unroll
        for (int r = 0; r < 16; ++r) acc[ni][r] = 0.f;

    #pragma unroll
    for (int kki = 0; kki < 16; ++kki) {
        const int kk = wave * 16 + kki;
        s8v af = *(const s8v*)&h2f[(((size_t)rt * 64 + kk) * 64 + lane) * 8];
        #pragma unroll
        for (int ni = 0; ni < 2; ++ni) {
            s8v bf = *(const s8v*)&W3Tf[(((size_t)ni * 64 + kk) * 64 + lane) * 8];
            acc[ni] = __builtin_amdgcn_mfma_f32_32x32x16_bf16(af, bf, acc[ni], 0, 0, 0);
        }
    }
    const int l31 = lane & 31, lh = lane >> 5;
    #pragma unroll
    for (int ni = 0; ni < 2; ++ni)
        #pragma unroll
        for (int r = 0; r < 16; ++r)
            red[wave][(r & 3) + ((r >> 2) << 3) + lh * 4][ni * 32 + l31] = acc[ni][r];
    __syncthreads();

    #pragma unroll
    for (int i = 0; i < 8; ++i) {
        int o = t * 8 + i;
        int row = o >> 6, col = o & 63;
        float s = red[0][row][col] + red[1][row][col] + red[2][row][col] + red[3][row][col] + b3[col];
        out[(size_t)(rt * 32 + row) * 65 + 1 + col] = s;
    }
    if (t < 32) out[(size_t)(rt * 32 + t) * 65] = -trJ[rt * 32 + t];
}

// ---------------------------------------------------------------------------
extern "C" void kernel_launch(void* const* d_in, const int* in_sizes, int n_in,
                              void* d_out, int out_size, void* d_ws, size_t ws_size,
                              hipStream_t stream) {
    const float* x  = (const float*)d_in[0];
    const float* W1 = (const float*)d_in[1];
    const float* b1 = (const float*)d_in[2];
    const float* W2 = (const float*)d_in[3];
    const float* b2 = (const float*)d_in[4];
    const float* W3 = (const float*)d_in[5];
    const float* b3 = (const float*)d_in[6];
    float* out = (float*)d_out;

    char* ws = (char*)d_ws;
    u16*   h1b = (u16*)(ws);                                  //  8 MB (row-major)
    u16*   g1b = (u16*)(ws + (size_t)( 8u << 20));            //  8 MB (row-major)
    u16*   h2f = (u16*)(ws + (size_t)(16u << 20));            //  8 MB (frag layout)
    u16*   W2T = (u16*)(ws + (size_t)(24u << 20));            //  2 MB (frag layout)
    u16*   VTb = (u16*)(ws + (size_t)(26u << 20));            //  2 MB (frag layout)
    float* trJ = (float*)(ws + (size_t)(28u << 20));          // 16 KB
    u16*   xbb = (u16*)(ws + (size_t)(28u << 20) + 65536);    // 512 KB
    u16*   W1T = (u16*)(ws + (size_t)(28u << 20) + 65536 + 524288);             // 128 KB
    u16*   W3T = (u16*)(ws + (size_t)(28u << 20) + 65536 + 524288 + 131072);    // 128 KB (frag)

    cnf_prep <<<dim3(32, 32), 256, 0, stream>>>(x, W1, W2, W3, W2T, VTb, xbb, W1T, W3T, trJ);
    cnf_gemm1<<<dim3(32, 16), 256, 0, stream>>>(xbb, W1T, b1, h1b, g1b);
    cnf_mid  <<<dim3(32, 8),  512, 0, stream>>>(h1b, g1b, W2T, VTb, b2, h2f, trJ);
    cnf_out  <<<128,          256, 0, stream>>>(h2f, W3T, b3, trJ, out);
}